// Round 5
// baseline (1900.015 us; speedup 1.0000x reference)
//
#include <hip/hip_runtime.h>
#include <hip/hip_bf16.h>

#define BATCH 128
#define SEQ   80
#define EMB   100
#define UNITS 2048
#define EPAD  128   // K-pad for the embedding matmul (100 -> 128)

typedef __attribute__((ext_vector_type(8))) short bf16x8;
typedef __attribute__((ext_vector_type(4))) float f32x4;

static __device__ __forceinline__ short f2bf(float f) {
  __hip_bfloat16 h = __float2bfloat16(f);
  return *reinterpret_cast<short*>(&h);
}
static __device__ __forceinline__ float bf2f(short s) {
  __hip_bfloat16 h = *reinterpret_cast<__hip_bfloat16*>(&s);
  return __bfloat162float(h);
}

// Packed fragment layouts (nch = K/32):
//  A-pack (h state, E): elem(row m, k) at [r=m>>4][kk=k>>5][lane=(m&15)|(((k>>3)&3)<<4)][j=k&7]
//  B-pack (weights):    elem(k, col n) at [c=n>>4][kk=k>>5][lane=(n&15)|(((k>>3)&3)<<4)][j=k&7]
// Both are [..][64 lanes][8] units of 1 KB.

__global__ __launch_bounds__(256) void pack_b_kernel(
    const float* __restrict__ src, int Ksrc, int N, int nch, int totalUnits,
    short* __restrict__ dst) {
  int lane = threadIdx.x & 63;
  int u = blockIdx.x * 4 + (threadIdx.x >> 6);
  if (u >= totalUnits) return;
  int c  = u / nch;
  int kk = u - c * nch;
  int n  = c * 16 + (lane & 15);
  int k0 = kk * 32 + ((lane >> 4) << 3);
  bf16x8 v;
#pragma unroll
  for (int j = 0; j < 8; ++j) {
    int k = k0 + j;
    float f = (k < Ksrc) ? src[k * N + n] : 0.f;
    v[j] = f2bf(f);
  }
  *reinterpret_cast<bf16x8*>(dst + (u * 64 + lane) * 8) = v;
}

__global__ __launch_bounds__(256) void pack_e_kernel(
    const int* __restrict__ tokens, const float* __restrict__ emb,
    short* __restrict__ Ep) {
  int idx = blockIdx.x * 256 + threadIdx.x;   // (t,r,kk,lane)
  if (idx >= SEQ * 8 * 4 * 64) return;
  int lane = idx & 63;
  int kk = (idx >> 6) & 3;
  int r  = (idx >> 8) & 7;
  int t  = idx >> 11;
  int b  = r * 16 + (lane & 15);
  int k0 = kk * 32 + ((lane >> 4) << 3);
  int tok = tokens[b * SEQ + t];
  bf16x8 v;
#pragma unroll
  for (int j = 0; j < 8; ++j) {
    int k = k0 + j;
    v[j] = (k < EMB) ? f2bf(emb[tok * EMB + k]) : (short)0;
  }
  *reinterpret_cast<bf16x8*>(Ep + (size_t)idx * 8) = v;
}

// ---------------------------------------------------------------------------
// Diagonal-wavefront GEMM stage.
//  - A fragments: registers, per-lane global loads, depth-1 prefetch (2 sets).
//  - B fragments: LDS ring-5 (80 KB), global_load_lds, depth-3, counted vmcnt,
//    ONE barrier per step (overwrite distance 4 mod 5 -> race-free).
// Block = 64x64 tile, 4 waves (2 wr x 2 wc) x 32x32, BK=128 (4 kk) per step.
// ---------------------------------------------------------------------------
#define MFMA(a, b, c) __builtin_amdgcn_mfma_f32_16x16x32_bf16((a), (b), (c), 0, 0, 0)

static __device__ __forceinline__ void gload16(const void* g, void* l) {
  __builtin_amdgcn_global_load_lds(
      (const __attribute__((address_space(1))) void*)g,
      (__attribute__((address_space(3))) void*)l, 16, 0, 0);
}

struct AF { bf16x8 v[2][4]; };

static __device__ __forceinline__ AF loadA(const char* a1pT, const char* a2pT,
                                           int steps0, size_t str1, int gs) {
  AF f;
  const char* base;
  size_t rstr;
  if (gs < steps0) { base = a1pT + (size_t)gs * 4096; rstr = str1; }
  else             { base = a2pT + (size_t)(gs - steps0) * 4096; rstr = 65536; }
#pragma unroll
  for (int x = 0; x < 2; ++x)
#pragma unroll
    for (int kq = 0; kq < 4; ++kq)
      f.v[x][kq] = *(const bf16x8*)(base + (size_t)x * rstr + kq * 1024);
  return f;
}

#define WAITV(N) asm volatile("s_waitcnt vmcnt(" #N ")" ::: "memory")

__global__ __launch_bounds__(256) void diag_kernel(
    const short* __restrict__ Ep,
    const short* __restrict__ W0p, const short* __restrict__ U0p,
    const short* __restrict__ Wsp, const short* __restrict__ Usp,
    const float* __restrict__ b0, const float* __restrict__ b1,
    short* __restrict__ hbase, int s) {
  __shared__ char ldsB[5][16384];   // ring-5 of B step-panels (16 KB each)

  const int tid  = threadIdx.x;
  const int lane = tid & 63;
  const int w    = tid >> 6;       // wave id; also the kq this thread stages
  const int wr   = w & 1, wc = w >> 1;

  // XCD-affine mapping: xcd = bid & 7 owns 4 consecutive cb's x all rb's
  int bid = blockIdx.x;
  int xcd = bid & 7, idx = bid >> 3;
  int cb  = xcd * 4 + (idx & 3);   // 0..31
  int rb  = idx >> 2;              // 0..7
  int l   = rb >> 1;
  int t   = s - l;
  if (t < 0 || t >= SEQ) return;

  const size_t hsz = (size_t)8 * 64 * 64 * 8;
  const int pw = s & 1, pr = pw ^ 1;
  auto hb = [&](int ll, int p) { return hbase + (size_t)(ll * 2 + p) * hsz; };

  const short *A1, *B1, *A2, *B2;
  const float* bias;
  int steps0;
  size_t str1;   // r/c unit stride of segment-1 operands (nch1 * 1024 B)
  if (l == 0) {
    A1 = Ep + (size_t)t * 16384; B1 = W0p; steps0 = 1;  str1 = 4096;
    A2 = hb(0, pr); B2 = U0p; bias = b0;
  } else {
    A1 = hb(l - 1, pr); B1 = Wsp; steps0 = 16; str1 = 65536;
    A2 = hb(l, pr);     B2 = Usp; bias = b1;
  }
  const int rloc0 = (rb & 1) * 4;    // layer-local r-tile base
  const int ct0   = cb * 4;          // global c-tile base
  const int total = steps0 + 16;
  const int rt0   = rloc0 + wr * 2;  // this wave's first r-tile

  // per-thread base pointers
  const size_t lb16 = (size_t)lane * 16;
  const char* a1pT = (const char*)A1 + (size_t)rt0 * str1 + lb16;
  const char* a2pT = (const char*)A2 + (size_t)rt0 * 65536 + lb16;
  const char* b1pT = (const char*)B1 + ((size_t)ct0 * str1) + (size_t)w * 1024 + lb16;
  const char* b2pT = (const char*)B2 + ((size_t)ct0 * 65536) + (size_t)w * 1024 + lb16;
  char* ldsB0 = &ldsB[0][0];

  auto issueB = [&](int gs) {
    char* dst = ldsB0 + (size_t)(gs % 5) * 16384 + (size_t)tid * 16;
    const char* src;
    size_t cstr;
    if (gs < steps0) { src = b1pT + (size_t)gs * 4096; cstr = str1; }
    else             { src = b2pT + (size_t)(gs - steps0) * 4096; cstr = 65536; }
#pragma unroll
    for (int rnd = 0; rnd < 4; ++rnd)
      gload16(src + rnd * cstr, dst + rnd * 4096);
  };

  f32x4 acc[2][2];
#pragma unroll
  for (int x = 0; x < 2; ++x)
#pragma unroll
    for (int y = 0; y < 2; ++y) acc[x][y] = (f32x4){0.f, 0.f, 0.f, 0.f};

  auto computeStep = [&](const char* lb, const AF& a) {
    bf16x8 bv[2][4];
#pragma unroll
    for (int y = 0; y < 2; ++y)
#pragma unroll
      for (int kq = 0; kq < 4; ++kq)
        bv[y][kq] = *(const bf16x8*)(lb + ((wc * 2 + y) * 4096 + kq * 1024) + lb16);
#pragma unroll
    for (int kq = 0; kq < 4; ++kq)
#pragma unroll
      for (int x = 0; x < 2; ++x)
#pragma unroll
        for (int y = 0; y < 2; ++y)
          acc[x][y] = MFMA(a.v[x][kq], bv[y][kq], acc[x][y]);
  };

  // STEP(g): prefetch A(g+1), issue B(g+3), wait exact vmcnt for B(g), barrier,
  // compute step g. Wait constants = #vmem ops issued after B(g)'s 4 gloads.
#define STEP(G, ACUR, ANXT)                                          \
  do {                                                               \
    const int g_ = (G);                                              \
    if (g_ + 1 < total) ANXT = loadA(a1pT, a2pT, steps0, str1, g_ + 1); \
    if (g_ + 3 < total) issueB(g_ + 3);                              \
    if (g_ == 0) WAITV(20);                                          \
    else if (g_ == 1) WAITV(28);                                     \
    else if (g_ == total - 3) WAITV(32);                             \
    else if (g_ == total - 2) WAITV(28);                             \
    else if (g_ == total - 1) WAITV(16);                             \
    else WAITV(36);                                                  \
    __builtin_amdgcn_s_barrier();                                    \
    __builtin_amdgcn_sched_barrier(0);                               \
    computeStep(ldsB0 + (size_t)(g_ % 5) * 16384, ACUR);             \
  } while (0)

  AF a0, a1;
  a0 = loadA(a1pT, a2pT, steps0, str1, 0);
  issueB(0); issueB(1); issueB(2);

  for (int g = 0; g < total; g += 2) {
    STEP(g, a0, a1);
    if (g + 1 < total) STEP(g + 1, a1, a0);
  }
#undef STEP

  // Epilogue: bias + tanh, store into A-pack layout of h_l (parity pw).
  // C/D layout: col = lane&15, row = (lane>>4)*4 + i.
  short* H = hb(l, pw);
  const int lo = lane & 15, hi = lane >> 4;
  const int mb = (rb & 1) * 64 + wr * 32;
  const int nb = cb * 64 + wc * 32;
  const float bv0 = bias[nb + lo];
  const float bv1 = bias[nb + 16 + lo];
#pragma unroll
  for (int x = 0; x < 2; ++x)
#pragma unroll
    for (int y = 0; y < 2; ++y) {
      float bbv = y ? bv1 : bv0;
#pragma unroll
      for (int i = 0; i < 4; ++i) {
        int m = mb + x * 16 + hi * 4 + i;
        int n = nb + y * 16 + lo;
        float z = acc[x][y][i] + bbv;
        float e = __expf(2.f * z);
        float th = 1.f - 2.f / (e + 1.f);
        int r  = m >> 4, kk = n >> 5;
        int lp = (m & 15) | (((n >> 3) & 3) << 4);
        H[(((size_t)r * 64 + kk) * 64 + lp) * 8 + (n & 7)] = f2bf(th);
      }
    }
}

// ---------------------------------------------------------------------------
// Output head: out[b] = sigmoid(h3[b] . Wo + bo); h3 in A-pack layout.
// ---------------------------------------------------------------------------
__global__ __launch_bounds__(256) void head_kernel(
    const short* __restrict__ h3, const float* __restrict__ Wo,
    const float* __restrict__ bo, float* __restrict__ out) {
  __shared__ float sred[4];
  int b = blockIdx.x, tid = threadIdx.x;
  int kk = tid >> 2, hi = tid & 3;
  const bf16x8 v = *reinterpret_cast<const bf16x8*>(
      h3 + (((size_t)(b >> 4) * 64 + kk) * 64 + ((b & 15) | (hi << 4))) * 8);
  int k0 = kk * 32 + hi * 8;
  float acc = 0.f;
#pragma unroll
  for (int j = 0; j < 8; ++j) acc += bf2f(v[j]) * Wo[k0 + j];
  for (int off = 32; off > 0; off >>= 1) acc += __shfl_down(acc, off);
  if ((tid & 63) == 0) sred[tid >> 6] = acc;
  __syncthreads();
  if (tid == 0) {
    float z = sred[0] + sred[1] + sred[2] + sred[3] + bo[0];
    out[b] = 1.f / (1.f + expf(-z));
  }
}

extern "C" void kernel_launch(void* const* d_in, const int* in_sizes, int n_in,
                              void* d_out, int out_size, void* d_ws, size_t ws_size,
                              hipStream_t stream) {
  const int*   tokens = (const int*)d_in[0];
  const float* emb    = (const float*)d_in[1];
  const float* W0     = (const float*)d_in[2];
  const float* U0     = (const float*)d_in[3];
  const float* b0     = (const float*)d_in[4];
  const float* W1     = (const float*)d_in[5];
  const float* U1     = (const float*)d_in[6];
  const float* b1     = (const float*)d_in[7];
  const float* Wo     = (const float*)d_in[8];
  const float* bo     = (const float*)d_in[9];
  float* out = (float*)d_out;
  short* ws  = (short*)d_ws;

  const size_t W0P_SZ = (size_t)128 * 4 * 512;     // 262144
  const size_t UP_SZ  = (size_t)128 * 64 * 512;    // 4194304
  const size_t EP_SZ  = (size_t)SEQ * 16384;       // 1310720
  const size_t H_SZ   = (size_t)8 * 64 * 64 * 8;   // 262144 per buffer

  short* W0p = ws;
  short* U0p = W0p + W0P_SZ;
  short* W1p = U0p + UP_SZ;
  short* U1p = W1p + UP_SZ;
  short* Ep  = U1p + UP_SZ;
  short* hbase = Ep + EP_SZ;

  {
    int unitsW0 = (UNITS / 16) * (EPAD / 32);   // 512
    pack_b_kernel<<<(unitsW0 + 3) / 4, 256, 0, stream>>>(W0, EMB, UNITS, EPAD / 32, unitsW0, W0p);
    int unitsU = (UNITS / 16) * (UNITS / 32);   // 8192
    pack_b_kernel<<<(unitsU + 3) / 4, 256, 0, stream>>>(U0, UNITS, UNITS, UNITS / 32, unitsU, U0p);
    pack_b_kernel<<<(unitsU + 3) / 4, 256, 0, stream>>>(W1, UNITS, UNITS, UNITS / 32, unitsU, W1p);
    pack_b_kernel<<<(unitsU + 3) / 4, 256, 0, stream>>>(U1, UNITS, UNITS, UNITS / 32, unitsU, U1p);
    int ne = SEQ * 8 * 4 * 64;
    pack_e_kernel<<<(ne + 255) / 256, 256, 0, stream>>>(tokens, emb, Ep);
  }

  // zero all 8 h double-buffers (provides h_l[-1] = 0)
  hipMemsetAsync(hbase, 0, 8u * H_SZ * 2u, stream);

  // ---- 83 diagonals: s = t + l ----
  for (int s = 0; s <= SEQ - 1 + 3; ++s) {
    diag_kernel<<<256, 256, 0, stream>>>(Ep, W0p, U0p, W1p, U1p, b0, b1, hbase, s);
  }

  // final head: h3[SEQ-1] written at diagonal 82 (parity 0)
  head_kernel<<<BATCH, 256, 0, stream>>>(hbase + 6 * H_SZ, Wo, bo, out);
}

// Round 6
// 1833.727 us; speedup vs baseline: 1.0361x; 1.0361x over previous
//
#include <hip/hip_runtime.h>
#include <hip/hip_bf16.h>

#define BATCH 128
#define SEQ   80
#define EMB   100
#define UNITS 2048
#define EPAD  128   // K-pad for the embedding matmul (100 -> 128)

typedef __attribute__((ext_vector_type(8))) short bf16x8;
typedef __attribute__((ext_vector_type(4))) float f32x4;

static __device__ __forceinline__ short f2bf(float f) {
  __hip_bfloat16 h = __float2bfloat16(f);
  return *reinterpret_cast<short*>(&h);
}
static __device__ __forceinline__ float bf2f(short s) {
  __hip_bfloat16 h = *reinterpret_cast<__hip_bfloat16*>(&s);
  return __bfloat162float(h);
}

// Packed fragment layouts (nch = K/32):
//  A-pack (h state, E): elem(row m, k) at [r=m>>4][kk=k>>5][lane=(m&15)|(((k>>3)&3)<<4)][j=k&7]
//  B-pack (weights):    elem(k, col n) at [c=n>>4][kk=k>>5][lane=(n&15)|(((k>>3)&3)<<4)][j=k&7]
// Both are [..][64 lanes][8] units of 1 KB.

__global__ __launch_bounds__(256) void pack_b_kernel(
    const float* __restrict__ src, int Ksrc, int N, int nch, int totalUnits,
    short* __restrict__ dst) {
  int lane = threadIdx.x & 63;
  int u = blockIdx.x * 4 + (threadIdx.x >> 6);
  if (u >= totalUnits) return;
  int c  = u / nch;
  int kk = u - c * nch;
  int n  = c * 16 + (lane & 15);
  int k0 = kk * 32 + ((lane >> 4) << 3);
  bf16x8 v;
#pragma unroll
  for (int j = 0; j < 8; ++j) {
    int k = k0 + j;
    float f = (k < Ksrc) ? src[k * N + n] : 0.f;
    v[j] = f2bf(f);
  }
  *reinterpret_cast<bf16x8*>(dst + (u * 64 + lane) * 8) = v;
}

__global__ __launch_bounds__(256) void pack_e_kernel(
    const int* __restrict__ tokens, const float* __restrict__ emb,
    short* __restrict__ Ep) {
  int idx = blockIdx.x * 256 + threadIdx.x;   // (t,r,kk,lane)
  if (idx >= SEQ * 8 * 4 * 64) return;
  int lane = idx & 63;
  int kk = (idx >> 6) & 3;
  int r  = (idx >> 8) & 7;
  int t  = idx >> 11;
  int b  = r * 16 + (lane & 15);
  int k0 = kk * 32 + ((lane >> 4) << 3);
  int tok = tokens[b * SEQ + t];
  bf16x8 v;
#pragma unroll
  for (int j = 0; j < 8; ++j) {
    int k = k0 + j;
    v[j] = (k < EMB) ? f2bf(emb[tok * EMB + k]) : (short)0;
  }
  *reinterpret_cast<bf16x8*>(Ep + (size_t)idx * 8) = v;
}

// ---------------------------------------------------------------------------
// Diagonal-wavefront GEMM stage.
//  - A panels: LDS ring-6 (96 KB), global_load_lds depth-4, ONE barrier/step.
//  - B fragments (weights, XCD-L2-warm): registers, explicit asm
//    global_load_dwordx4, depth-2 prefetch (two named sets, unroll-2).
//  - All vmem is explicit -> exact counted vmcnt(12/8/0), never drains mid-loop.
// Block = 64x64 tile, 4 waves (2 wr x 2 wc) x 32x32, BK=128 (4 kk) per step.
// ---------------------------------------------------------------------------
#define MFMA(a, b, c) __builtin_amdgcn_mfma_f32_16x16x32_bf16((a), (b), (c), 0, 0, 0)

static __device__ __forceinline__ void gload16(const void* g, void* l) {
  __builtin_amdgcn_global_load_lds(
      (const __attribute__((address_space(1))) void*)g,
      (__attribute__((address_space(3))) void*)l, 16, 0, 0);
}

struct BF { bf16x8 v[2][4]; };

#define WAITV(N) asm volatile("s_waitcnt vmcnt(" #N ")" ::: "memory")

__global__ __launch_bounds__(256) void diag_kernel(
    const short* __restrict__ Ep,
    const short* __restrict__ W0p, const short* __restrict__ U0p,
    const short* __restrict__ Wsp, const short* __restrict__ Usp,
    const float* __restrict__ b0, const float* __restrict__ b1,
    short* __restrict__ hbase, int s) {
  __shared__ char ldsA[6][16384];   // ring-6 of A step-panels (16 KB each)

  const int tid  = threadIdx.x;
  const int lane = tid & 63;
  const int w    = tid >> 6;       // wave id; also the kq this thread stages
  const int wr   = w & 1, wc = w >> 1;

  // XCD-affine mapping: xcd = bid & 7 owns 4 consecutive cb's x all rb's
  int bid = blockIdx.x;
  int xcd = bid & 7, idx = bid >> 3;
  int cb  = xcd * 4 + (idx & 3);   // 0..31
  int rb  = idx >> 2;              // 0..7
  int l   = rb >> 1;
  int t   = s - l;
  if (t < 0 || t >= SEQ) return;

  const size_t hsz = (size_t)8 * 64 * 64 * 8;
  const int pw = s & 1, pr = pw ^ 1;
  auto hb = [&](int ll, int p) { return hbase + (size_t)(ll * 2 + p) * hsz; };

  const short *A1, *B1, *A2, *B2;
  const float* bias;
  int steps0;
  size_t str1;   // r/c unit stride (bytes) of segment-1 operands = nch1*1024
  if (l == 0) {
    A1 = Ep + (size_t)t * 16384; B1 = W0p; steps0 = 1;  str1 = 4096;
    A2 = hb(0, pr); B2 = U0p; bias = b0;
  } else {
    A1 = hb(l - 1, pr); B1 = Wsp; steps0 = 16; str1 = 65536;
    A2 = hb(l, pr);     B2 = Usp; bias = b1;
  }
  const int rloc0 = (rb & 1) * 4;    // layer-local r-tile base
  const int ct0   = cb * 4;          // global c-tile base
  const int total = steps0 + 16;

  // per-thread base pointers
  const size_t lb16  = (size_t)lane * 16;
  const size_t koffq = (size_t)w * 1024 + lb16;
  const char* a1pT = (const char*)A1 + (size_t)rloc0 * str1 + koffq;
  const char* a2pT = (const char*)A2 + (size_t)rloc0 * 65536 + koffq;
  const char* b1p0 = (const char*)B1 + (size_t)(ct0 + wc * 2 + 0) * str1 + lb16;
  const char* b1p1 = (const char*)B1 + (size_t)(ct0 + wc * 2 + 1) * str1 + lb16;
  const char* b2p0 = (const char*)B2 + (size_t)(ct0 + wc * 2 + 0) * 65536 + lb16;
  const char* b2p1 = (const char*)B2 + (size_t)(ct0 + wc * 2 + 1) * 65536 + lb16;
  char* ldsA0 = &ldsA[0][0] + (size_t)tid * 16;

  // stage one A step-panel (16 KB): 4 gload_lds of 16B per thread
  auto issueA = [&](int gs) {
    char* dst = ldsA0 + (size_t)(gs % 6) * 16384;
    const char* src;
    size_t rstr;
    if (gs < steps0) { src = a1pT + (size_t)gs * 4096; rstr = str1; }
    else             { src = a2pT + (size_t)(gs - steps0) * 4096; rstr = 65536; }
#pragma unroll
    for (int rt = 0; rt < 4; ++rt)
      gload16(src + rt * rstr, dst + rt * 4096);
  };

  // load this wave's 8 B fragments for step GS into register set BN (asm)
#define LOADB(BN, GS)                                                        \
  do {                                                                       \
    const int gs_ = (GS);                                                    \
    const char *bb0_, *bb1_;                                                 \
    if (gs_ < steps0) {                                                      \
      size_t o_ = (size_t)gs_ * 4096;                                        \
      bb0_ = b1p0 + o_; bb1_ = b1p1 + o_;                                    \
    } else {                                                                 \
      size_t o_ = (size_t)(gs_ - steps0) * 4096;                             \
      bb0_ = b2p0 + o_; bb1_ = b2p1 + o_;                                    \
    }                                                                        \
    _Pragma("unroll")                                                        \
    for (int kq = 0; kq < 4; ++kq) {                                         \
      asm volatile("global_load_dwordx4 %0, %1, off"                         \
                   : "=v"(BN.v[0][kq]) : "v"(bb0_ + kq * 1024));             \
      asm volatile("global_load_dwordx4 %0, %1, off"                         \
                   : "=v"(BN.v[1][kq]) : "v"(bb1_ + kq * 1024));             \
    }                                                                        \
  } while (0)

  f32x4 acc[2][2];
#pragma unroll
  for (int x = 0; x < 2; ++x)
#pragma unroll
    for (int y = 0; y < 2; ++y) acc[x][y] = (f32x4){0.f, 0.f, 0.f, 0.f};

  auto computeStep = [&](int g, const BF& Bf) {
    const char* base = &ldsA[g % 6][0];
    bf16x8 av[2][4];
#pragma unroll
    for (int x = 0; x < 2; ++x)
#pragma unroll
      for (int kq = 0; kq < 4; ++kq)
        av[x][kq] = *(const bf16x8*)(base + (((wr * 2 + x) * 4 + kq) << 10) + lb16);
#pragma unroll
    for (int kq = 0; kq < 4; ++kq)
#pragma unroll
      for (int x = 0; x < 2; ++x)
#pragma unroll
        for (int y = 0; y < 2; ++y)
          acc[x][y] = MFMA(av[x][kq], Bf.v[y][kq], acc[x][y]);
  };

  // STEP(g): issue A(g+4), load B(g+1), exact-wait for A(g)+B(g), barrier,
  // compute g. Steady wait = ops issued after B(g): A(g+4)[4] + B(g+1)[8] = 12.
#define STEP(G, BCUR, BNXT)                                          \
  do {                                                               \
    const int g_ = (G);                                              \
    if (g_ + 4 < total) issueA(g_ + 4);                              \
    if (g_ + 1 < total) LOADB(BNXT, g_ + 1);                         \
    if (g_ < total - 4) { WAITV(12); }                               \
    else if (g_ == total - 1) { WAITV(0); }                          \
    else { WAITV(8); }                                               \
    __builtin_amdgcn_s_barrier();                                    \
    __builtin_amdgcn_sched_barrier(0);                               \
    computeStep(g_, BCUR);                                           \
    __builtin_amdgcn_sched_barrier(0);                               \
  } while (0)

  BF Bq0, Bq1;
  LOADB(Bq0, 0);
  issueA(0); issueA(1); issueA(2); issueA(3);

  for (int g = 0; g < total; g += 2) {
    STEP(g, Bq0, Bq1);
    if (g + 1 < total) STEP(g + 1, Bq1, Bq0);
  }
#undef STEP
#undef LOADB

  // Epilogue: bias + tanh, store into A-pack layout of h_l (parity pw).
  // C/D layout: col = lane&15, row = (lane>>4)*4 + i.
  short* H = hb(l, pw);
  const int lo = lane & 15, hi = lane >> 4;
  const int mb = (rb & 1) * 64 + wr * 32;
  const int nb = cb * 64 + wc * 32;
  const float bv0 = bias[nb + lo];
  const float bv1 = bias[nb + 16 + lo];
#pragma unroll
  for (int x = 0; x < 2; ++x)
#pragma unroll
    for (int y = 0; y < 2; ++y) {
      float bbv = y ? bv1 : bv0;
#pragma unroll
      for (int i = 0; i < 4; ++i) {
        int m = mb + x * 16 + hi * 4 + i;
        int n = nb + y * 16 + lo;
        float z = acc[x][y][i] + bbv;
        float e = __expf(2.f * z);
        float th = 1.f - 2.f / (e + 1.f);
        int r  = m >> 4, kk = n >> 5;
        int lp = (m & 15) | (((n >> 3) & 3) << 4);
        H[(((size_t)r * 64 + kk) * 64 + lp) * 8 + (n & 7)] = f2bf(th);
      }
    }
}

// ---------------------------------------------------------------------------
// Output head: out[b] = sigmoid(h3[b] . Wo + bo); h3 in A-pack layout.
// ---------------------------------------------------------------------------
__global__ __launch_bounds__(256) void head_kernel(
    const short* __restrict__ h3, const float* __restrict__ Wo,
    const float* __restrict__ bo, float* __restrict__ out) {
  __shared__ float sred[4];
  int b = blockIdx.x, tid = threadIdx.x;
  int kk = tid >> 2, hi = tid & 3;
  const bf16x8 v = *reinterpret_cast<const bf16x8*>(
      h3 + (((size_t)(b >> 4) * 64 + kk) * 64 + ((b & 15) | (hi << 4))) * 8);
  int k0 = kk * 32 + hi * 8;
  float acc = 0.f;
#pragma unroll
  for (int j = 0; j < 8; ++j) acc += bf2f(v[j]) * Wo[k0 + j];
  for (int off = 32; off > 0; off >>= 1) acc += __shfl_down(acc, off);
  if ((tid & 63) == 0) sred[tid >> 6] = acc;
  __syncthreads();
  if (tid == 0) {
    float z = sred[0] + sred[1] + sred[2] + sred[3] + bo[0];
    out[b] = 1.f / (1.f + expf(-z));
  }
}

extern "C" void kernel_launch(void* const* d_in, const int* in_sizes, int n_in,
                              void* d_out, int out_size, void* d_ws, size_t ws_size,
                              hipStream_t stream) {
  const int*   tokens = (const int*)d_in[0];
  const float* emb    = (const float*)d_in[1];
  const float* W0     = (const float*)d_in[2];
  const float* U0     = (const float*)d_in[3];
  const float* b0     = (const float*)d_in[4];
  const float* W1     = (const float*)d_in[5];
  const float* U1     = (const float*)d_in[6];
  const float* b1     = (const float*)d_in[7];
  const float* Wo     = (const float*)d_in[8];
  const float* bo     = (const float*)d_in[9];
  float* out = (float*)d_out;
  short* ws  = (short*)d_ws;

  const size_t W0P_SZ = (size_t)128 * 4 * 512;     // 262144
  const size_t UP_SZ  = (size_t)128 * 64 * 512;    // 4194304
  const size_t EP_SZ  = (size_t)SEQ * 16384;       // 1310720
  const size_t H_SZ   = (size_t)8 * 64 * 64 * 8;   // 262144 per buffer

  short* W0p = ws;
  short* U0p = W0p + W0P_SZ;
  short* W1p = U0p + UP_SZ;
  short* U1p = W1p + UP_SZ;
  short* Ep  = U1p + UP_SZ;
  short* hbase = Ep + EP_SZ;

  {
    int unitsW0 = (UNITS / 16) * (EPAD / 32);   // 512
    pack_b_kernel<<<(unitsW0 + 3) / 4, 256, 0, stream>>>(W0, EMB, UNITS, EPAD / 32, unitsW0, W0p);
    int unitsU = (UNITS / 16) * (UNITS / 32);   // 8192
    pack_b_kernel<<<(unitsU + 3) / 4, 256, 0, stream>>>(U0, UNITS, UNITS, UNITS / 32, unitsU, U0p);
    pack_b_kernel<<<(unitsU + 3) / 4, 256, 0, stream>>>(W1, UNITS, UNITS, UNITS / 32, unitsU, W1p);
    pack_b_kernel<<<(unitsU + 3) / 4, 256, 0, stream>>>(U1, UNITS, UNITS, UNITS / 32, unitsU, U1p);
    int ne = SEQ * 8 * 4 * 64;
    pack_e_kernel<<<(ne + 255) / 256, 256, 0, stream>>>(tokens, emb, Ep);
  }

  // zero all 8 h double-buffers (provides h_l[-1] = 0)
  hipMemsetAsync(hbase, 0, 8u * H_SZ * 2u, stream);

  // ---- 83 diagonals: s = t + l ----
  for (int s = 0; s <= SEQ - 1 + 3; ++s) {
    diag_kernel<<<256, 256, 0, stream>>>(Ep, W0p, U0p, W1p, U1p, b0, b1, hbase, s);
  }

  // final head: h3[SEQ-1] written at diagonal 82 (parity 0)
  head_kernel<<<BATCH, 256, 0, stream>>>(hbase + 6 * H_SZ, Wo, bo, out);
}

// Round 8
// 1524.152 us; speedup vs baseline: 1.2466x; 1.2031x over previous
//
#include <hip/hip_runtime.h>
#include <hip/hip_bf16.h>

#define BATCH 128
#define SEQ   80
#define EMB   100
#define UNITS 2048
#define EPAD  128   // K-pad for the embedding matmul (100 -> 128)

typedef __attribute__((ext_vector_type(8))) short bf16x8;
typedef __attribute__((ext_vector_type(4))) float f32x4;

static __device__ __forceinline__ short f2bf(float f) {
  __hip_bfloat16 h = __float2bfloat16(f);
  return *reinterpret_cast<short*>(&h);
}
static __device__ __forceinline__ float bf2f(short s) {
  __hip_bfloat16 h = *reinterpret_cast<__hip_bfloat16*>(&s);
  return __bfloat162float(h);
}

// Packed fragment layouts (nch = K/32):
//  A-pack (h state, E): elem(row m, k) at [r=m>>4][kk=k>>5][lane=(m&15)|(((k>>3)&3)<<4)][j=k&7]
//  B-pack (weights):    elem(k, col n) at [c=n>>4][kk=k>>5][lane=(n&15)|(((k>>3)&3)<<4)][j=k&7]
// Both are [..][64 lanes][8] units of 1 KB.

__global__ __launch_bounds__(256) void pack_b_kernel(
    const float* __restrict__ src, int Ksrc, int N, int nch, int totalUnits,
    short* __restrict__ dst) {
  int lane = threadIdx.x & 63;
  int u = blockIdx.x * 4 + (threadIdx.x >> 6);
  if (u >= totalUnits) return;
  int c  = u / nch;
  int kk = u - c * nch;
  int n  = c * 16 + (lane & 15);
  int k0 = kk * 32 + ((lane >> 4) << 3);
  bf16x8 v;
#pragma unroll
  for (int j = 0; j < 8; ++j) {
    int k = k0 + j;
    float f = (k < Ksrc) ? src[k * N + n] : 0.f;
    v[j] = f2bf(f);
  }
  *reinterpret_cast<bf16x8*>(dst + (u * 64 + lane) * 8) = v;
}

__global__ __launch_bounds__(256) void pack_e_kernel(
    const int* __restrict__ tokens, const float* __restrict__ emb,
    short* __restrict__ Ep) {
  int idx = blockIdx.x * 256 + threadIdx.x;   // (t,r,kk,lane)
  if (idx >= SEQ * 8 * 4 * 64) return;
  int lane = idx & 63;
  int kk = (idx >> 6) & 3;
  int r  = (idx >> 8) & 7;
  int t  = idx >> 11;
  int b  = r * 16 + (lane & 15);
  int k0 = kk * 32 + ((lane >> 4) << 3);
  int tok = tokens[b * SEQ + t];
  bf16x8 v;
#pragma unroll
  for (int j = 0; j < 8; ++j) {
    int k = k0 + j;
    v[j] = (k < EMB) ? f2bf(emb[tok * EMB + k]) : (short)0;
  }
  *reinterpret_cast<bf16x8*>(Ep + (size_t)idx * 8) = v;
}

// ---------------------------------------------------------------------------
// Diagonal-wavefront GEMM stage, K-split 8-wave structure (512 threads).
//  - Waves: wr = w&1 (rows), wc = (w>>1)&1 (cols), wk = w>>2 (K-half of step).
//  - A panels: LDS ring-4 (64 KB), global_load_lds depth-2, ONE barrier/step.
//  - B fragments: registers via explicit asm global_load_dwordx4 (twin waves
//    share addresses -> L1 dedup), depth-1 double-buffered.
//  - All vmem explicit. In-order vmcnt accounting: entering STEP(g) the
//    outstanding set is A(g+1)[2]+B(g)[4]; after issuing A(g+2)[2]+B(g+1)[4]
//    there are 12 and we must leave only the 6 NEWEST -> vmcnt(6).
//    Tail: total-2 -> vmcnt(4); total-1 -> vmcnt(0).  (r7 bug: 8/6/0 left
//    B(g)'s last 2 loads in flight -> NaN.)
//  - End: wk=1 partial accumulators reduced into wk=0 via LDS, wk=0 stores.
// Block = 64x64 tile; per wave per step: 4 ds_read_b128 + 4 b-loads + 8 MFMA.
// ---------------------------------------------------------------------------
#define MFMA(a, b, c) __builtin_amdgcn_mfma_f32_16x16x32_bf16((a), (b), (c), 0, 0, 0)

static __device__ __forceinline__ void gload16(const void* g, void* l) {
  __builtin_amdgcn_global_load_lds(
      (const __attribute__((address_space(1))) void*)g,
      (__attribute__((address_space(3))) void*)l, 16, 0, 0);
}

struct BF { bf16x8 v[2][2]; };   // [y][q]

#define WAITV(N) asm volatile("s_waitcnt vmcnt(" #N ")" ::: "memory")

__global__ __launch_bounds__(512) void diag_kernel(
    const short* __restrict__ Ep,
    const short* __restrict__ W0p, const short* __restrict__ U0p,
    const short* __restrict__ Wsp, const short* __restrict__ Usp,
    const float* __restrict__ b0, const float* __restrict__ b1,
    short* __restrict__ hbase, int s) {
  __shared__ char ldsA[4][16384];   // ring-4 of A step-panels (16 KB each)

  const int tid  = threadIdx.x;
  const int lane = tid & 63;
  const int w    = tid >> 6;
  const int wr = w & 1, wc = (w >> 1) & 1, wk = w >> 2;

  // XCD-affine mapping: xcd = bid & 7 owns 4 consecutive cb's x all rb's
  int bid = blockIdx.x;
  int xcd = bid & 7, idx = bid >> 3;
  int cb  = xcd * 4 + (idx & 3);   // 0..31
  int rb  = idx >> 2;              // 0..7
  int l   = rb >> 1;
  int t   = s - l;
  if (t < 0 || t >= SEQ) return;

  const size_t hsz = (size_t)8 * 64 * 64 * 8;
  const int pw = s & 1, pr = pw ^ 1;
  auto hb = [&](int ll, int p) { return hbase + (size_t)(ll * 2 + p) * hsz; };

  const short *A1, *B1, *A2, *B2;
  const float* bias;
  int steps0, nch1;
  if (l == 0) {
    A1 = Ep + (size_t)t * 16384; B1 = W0p; steps0 = 1;  nch1 = 4;
    A2 = hb(0, pr); B2 = U0p; bias = b0;
  } else {
    A1 = hb(l - 1, pr); B1 = Wsp; steps0 = 16; nch1 = 64;
    A2 = hb(l, pr);     B2 = Usp; bias = b1;
  }
  const int rloc0 = (rb & 1) * 4;    // layer-local r-tile base
  const int ct0   = cb * 4;          // global c-tile base
  const int total = steps0 + 16;

  // ---- staging coords: thread stages units (rt0, kqT) and (rt0+2, kqT) ----
  const int rt0 = tid >> 8;          // 0..1
  const int kqT = (tid >> 6) & 3;
  const size_t lb16 = (size_t)lane * 16;
  const char* a1T = (const char*)A1 + (((size_t)(rloc0 + rt0) * nch1 + kqT) << 10) + lb16;
  const char* a2T = (const char*)A2 + (((size_t)(rloc0 + rt0) * 64 + kqT) << 10) + lb16;
  const size_t aStr1 = (size_t)nch1 * 2048;   // rt -> rt+2 stride, segment 1
  char* ldsA0 = &ldsA[0][0] + (size_t)tid * 16;

  auto issueA = [&](int gs) {
    char* dst = ldsA0 + (size_t)(gs & 3) * 16384;
    const char* src; size_t rstr;
    if (gs < steps0) { src = a1T + (size_t)gs * 4096; rstr = aStr1; }
    else             { src = a2T + (size_t)(gs - steps0) * 4096; rstr = 131072; }
    gload16(src, dst);
    gload16(src + rstr, dst + 8192);
  };

  // ---- B register-path base pointers (per wave, cols ct0+wc*2+{0,1}) ----
  const char* b1T0 = (const char*)B1 + (((size_t)(ct0 + wc * 2 + 0) * nch1 + wk * 2) << 10) + lb16;
  const char* b1T1 = (const char*)B1 + (((size_t)(ct0 + wc * 2 + 1) * nch1 + wk * 2) << 10) + lb16;
  const char* b2T0 = (const char*)B2 + (((size_t)(ct0 + wc * 2 + 0) * 64 + wk * 2) << 10) + lb16;
  const char* b2T1 = (const char*)B2 + (((size_t)(ct0 + wc * 2 + 1) * 64 + wk * 2) << 10) + lb16;

#define LOADB(BN, GS)                                                         \
  do {                                                                        \
    const int gs_ = (GS);                                                     \
    const char *p0_, *p1_;                                                    \
    if (gs_ < steps0) {                                                       \
      size_t o_ = (size_t)gs_ * 4096;                                         \
      p0_ = b1T0 + o_; p1_ = b1T1 + o_;                                       \
    } else {                                                                  \
      size_t o_ = (size_t)(gs_ - steps0) * 4096;                              \
      p0_ = b2T0 + o_; p1_ = b2T1 + o_;                                       \
    }                                                                         \
    asm volatile("global_load_dwordx4 %0, %1, off" : "=v"(BN.v[0][0]) : "v"(p0_));        \
    asm volatile("global_load_dwordx4 %0, %1, off" : "=v"(BN.v[0][1]) : "v"(p0_ + 1024)); \
    asm volatile("global_load_dwordx4 %0, %1, off" : "=v"(BN.v[1][0]) : "v"(p1_));        \
    asm volatile("global_load_dwordx4 %0, %1, off" : "=v"(BN.v[1][1]) : "v"(p1_ + 1024)); \
  } while (0)

  f32x4 acc[2][2];
#pragma unroll
  for (int x = 0; x < 2; ++x)
#pragma unroll
    for (int y = 0; y < 2; ++y) acc[x][y] = (f32x4){0.f, 0.f, 0.f, 0.f};

  auto computeStep = [&](int g, const BF& Bf) {
    const char* base = &ldsA[g & 3][0];
    bf16x8 av[2][2];
#pragma unroll
    for (int x = 0; x < 2; ++x)
#pragma unroll
      for (int q = 0; q < 2; ++q)
        av[x][q] = *(const bf16x8*)(base + ((((wr * 2 + x) * 4 + (wk * 2 + q)) << 10) + lb16));
#pragma unroll
    for (int q = 0; q < 2; ++q)
#pragma unroll
      for (int x = 0; x < 2; ++x)
#pragma unroll
        for (int y = 0; y < 2; ++y)
          acc[x][y] = MFMA(av[x][q], Bf.v[y][q], acc[x][y]);
  };

  // STEP(g): issue A(g+2), load B(g+1); wait so A(g)+B(g) complete (leave only
  // the newest 6 = A(g+2)[2]+B(g+1)[4]); ONE barrier; compute g.
  // Ring-4 overwrite distance 3 mod 4 -> single barrier race-free.
#define STEP(G, BCUR, BNXT)                                          \
  do {                                                               \
    const int g_ = (G);                                              \
    if (g_ + 2 < total) issueA(g_ + 2);                              \
    if (g_ + 1 < total) LOADB(BNXT, g_ + 1);                         \
    if (g_ <= total - 3) { WAITV(6); }                               \
    else if (g_ == total - 2) { WAITV(4); }                          \
    else { WAITV(0); }                                               \
    __builtin_amdgcn_s_barrier();                                    \
    __builtin_amdgcn_sched_barrier(0);                               \
    computeStep(g_, BCUR);                                           \
    __builtin_amdgcn_sched_barrier(0);                               \
  } while (0)

  BF Bq0, Bq1;
  issueA(0); issueA(1);
  LOADB(Bq0, 0);

  for (int g = 0; g < total; g += 2) {
    STEP(g, Bq0, Bq1);
    if (g + 1 < total) STEP(g + 1, Bq1, Bq0);
  }
#undef STEP
#undef LOADB

  // ---- K-split reduction: wk=1 partials -> wk=0 via LDS (16 KB, slot 0) ----
  __syncthreads();
  if (wk == 1) {
#pragma unroll
    for (int x = 0; x < 2; ++x)
#pragma unroll
      for (int y = 0; y < 2; ++y)
        *(f32x4*)(&ldsA[0][0] + ((((size_t)(w & 3) * 4 + x * 2 + y) * 64 + lane) << 4)) = acc[x][y];
  }
  __syncthreads();
  if (wk == 1) return;
#pragma unroll
  for (int x = 0; x < 2; ++x)
#pragma unroll
    for (int y = 0; y < 2; ++y)
      acc[x][y] += *(const f32x4*)(&ldsA[0][0] + ((((size_t)(w & 3) * 4 + x * 2 + y) * 64 + lane) << 4));

  // Epilogue: bias + tanh, store into A-pack layout of h_l (parity pw).
  // C/D layout: col = lane&15, row = (lane>>4)*4 + i.
  short* H = hb(l, pw);
  const int lo = lane & 15, hi = lane >> 4;
  const int mb = (rb & 1) * 64 + wr * 32;
  const int nb = cb * 64 + wc * 32;
  const float bv0 = bias[nb + lo];
  const float bv1 = bias[nb + 16 + lo];
#pragma unroll
  for (int x = 0; x < 2; ++x)
#pragma unroll
    for (int y = 0; y < 2; ++y) {
      float bbv = y ? bv1 : bv0;
#pragma unroll
      for (int i = 0; i < 4; ++i) {
        int m = mb + x * 16 + hi * 4 + i;
        int n = nb + y * 16 + lo;
        float z = acc[x][y][i] + bbv;
        float e = __expf(2.f * z);
        float th = 1.f - 2.f / (e + 1.f);
        int r  = m >> 4, kk = n >> 5;
        int lp = (m & 15) | (((n >> 3) & 3) << 4);
        H[(((size_t)r * 64 + kk) * 64 + lp) * 8 + (n & 7)] = f2bf(th);
      }
    }
}

// ---------------------------------------------------------------------------
// Output head: out[b] = sigmoid(h3[b] . Wo + bo); h3 in A-pack layout.
// ---------------------------------------------------------------------------
__global__ __launch_bounds__(256) void head_kernel(
    const short* __restrict__ h3, const float* __restrict__ Wo,
    const float* __restrict__ bo, float* __restrict__ out) {
  __shared__ float sred[4];
  int b = blockIdx.x, tid = threadIdx.x;
  int kk = tid >> 2, hi = tid & 3;
  const bf16x8 v = *reinterpret_cast<const bf16x8*>(
      h3 + (((size_t)(b >> 4) * 64 + kk) * 64 + ((b & 15) | (hi << 4))) * 8);
  int k0 = kk * 32 + hi * 8;
  float acc = 0.f;
#pragma unroll
  for (int j = 0; j < 8; ++j) acc += bf2f(v[j]) * Wo[k0 + j];
  for (int off = 32; off > 0; off >>= 1) acc += __shfl_down(acc, off);
  if ((tid & 63) == 0) sred[tid >> 6] = acc;
  __syncthreads();
  if (tid == 0) {
    float z = sred[0] + sred[1] + sred[2] + sred[3] + bo[0];
    out[b] = 1.f / (1.f + expf(-z));
  }
}

extern "C" void kernel_launch(void* const* d_in, const int* in_sizes, int n_in,
                              void* d_out, int out_size, void* d_ws, size_t ws_size,
                              hipStream_t stream) {
  const int*   tokens = (const int*)d_in[0];
  const float* emb    = (const float*)d_in[1];
  const float* W0     = (const float*)d_in[2];
  const float* U0     = (const float*)d_in[3];
  const float* b0     = (const float*)d_in[4];
  const float* W1     = (const float*)d_in[5];
  const float* U1     = (const float*)d_in[6];
  const float* b1     = (const float*)d_in[7];
  const float* Wo     = (const float*)d_in[8];
  const float* bo     = (const float*)d_in[9];
  float* out = (float*)d_out;
  short* ws  = (short*)d_ws;

  const size_t W0P_SZ = (size_t)128 * 4 * 512;     // 262144
  const size_t UP_SZ  = (size_t)128 * 64 * 512;    // 4194304
  const size_t EP_SZ  = (size_t)SEQ * 16384;       // 1310720
  const size_t H_SZ   = (size_t)8 * 64 * 64 * 8;   // 262144 per buffer

  short* W0p = ws;
  short* U0p = W0p + W0P_SZ;
  short* W1p = U0p + UP_SZ;
  short* U1p = W1p + UP_SZ;
  short* Ep  = U1p + UP_SZ;
  short* hbase = Ep + EP_SZ;

  {
    int unitsW0 = (UNITS / 16) * (EPAD / 32);   // 512
    pack_b_kernel<<<(unitsW0 + 3) / 4, 256, 0, stream>>>(W0, EMB, UNITS, EPAD / 32, unitsW0, W0p);
    int unitsU = (UNITS / 16) * (UNITS / 32);   // 8192
    pack_b_kernel<<<(unitsU + 3) / 4, 256, 0, stream>>>(U0, UNITS, UNITS, UNITS / 32, unitsU, U0p);
    pack_b_kernel<<<(unitsU + 3) / 4, 256, 0, stream>>>(W1, UNITS, UNITS, UNITS / 32, unitsU, W1p);
    pack_b_kernel<<<(unitsU + 3) / 4, 256, 0, stream>>>(U1, UNITS, UNITS, UNITS / 32, unitsU, U1p);
    int ne = SEQ * 8 * 4 * 64;
    pack_e_kernel<<<(ne + 255) / 256, 256, 0, stream>>>(tokens, emb, Ep);
  }

  // zero all 8 h double-buffers (provides h_l[-1] = 0)
  hipMemsetAsync(hbase, 0, 8u * H_SZ * 2u, stream);

  // ---- 83 diagonals: s = t + l ----
  for (int s = 0; s <= SEQ - 1 + 3; ++s) {
    diag_kernel<<<256, 512, 0, stream>>>(Ep, W0p, U0p, W1p, U1p, b0, b1, hbase, s);
  }

  // final head: h3[SEQ-1] written at diagonal 82 (parity 0)
  head_kernel<<<BATCH, 256, 0, stream>>>(hbase + 6 * H_SZ, Wo, bo, out);
}